// Round 1
// baseline (7968.435 us; speedup 1.0000x reference)
//
#include <hip/hip_runtime.h>
#include <cstdint>
#include <cstddef>

typedef unsigned short u16;
typedef unsigned int   u32;
typedef unsigned long long u64;

typedef __attribute__((ext_vector_type(8))) short short8;
typedef __attribute__((ext_vector_type(4))) float f32x4;

#define NB_B 16
#define NT   64
#define NH   512
#define ND   512
#define NV   50257
#define NG   2048   // 4*H

__device__ __forceinline__ u16 f2bf(float f) {
    u32 u = __builtin_bit_cast(u32, f);
    return (u16)((u + 0x7FFFu + ((u >> 16) & 1u)) >> 16);   // RNE to bf16
}
__device__ __forceinline__ float bf2f(u16 h) {
    return __builtin_bit_cast(float, (u32)h << 16);
}
__device__ __forceinline__ float sigm(float x) { return 1.0f / (1.0f + expf(-x)); }

// ---------------- K0: split W_hh -> bf16 hi/lo, zero argmax slots ----------------
__global__ void k_prep(const float* __restrict__ Whh, u16* __restrict__ Whi,
                       u16* __restrict__ Wlo, u64* __restrict__ argm) {
    int i = blockIdx.x * 256 + threadIdx.x;
    if (i < NG * NH) {
        float f = Whh[i];
        u16 hi = f2bf(f);
        Whi[i] = hi;
        Wlo[i] = f2bf(f - bf2f(hi));
    }
    if (i < NB_B * NT) argm[i] = 0ull;
}

// ---------------- K1: combine = relu(concat(sh,oh) @ Wc^T + bc) ----------------
__global__ __launch_bounds__(256) void k_combine(
    const float* __restrict__ sh, const float* __restrict__ oh,
    const float* __restrict__ Wc, const float* __restrict__ bc,
    float* __restrict__ h0, float* __restrict__ rep_out) {
    __shared__ float x[1024];
    int b = blockIdx.x, tid = threadIdx.x;
    for (int i = tid; i < 1024; i += 256)
        x[i] = (i < NH) ? sh[b * NH + i] : oh[b * NH + i - NH];
    __syncthreads();
    for (int n = tid; n < NH; n += 256) {
        const float* wr = Wc + (size_t)n * 1024;
        float s = 0.f;
        #pragma unroll 4
        for (int k = 0; k < 1024; k += 4) {
            float4 w = *(const float4*)(wr + k);
            s += x[k] * w.x + x[k+1] * w.y + x[k+2] * w.z + x[k+3] * w.w;
        }
        s += bc[n];
        s = fmaxf(s, 0.f);
        h0[b * NH + n] = s;
        rep_out[b * NH + n] = s;
    }
}

// ---------------- K2: gather embedding rows (teacher forcing, BOS=1) ----------------
__global__ void k_gather(const int* __restrict__ targets, const float* __restrict__ E,
                         float* __restrict__ emb) {
    int bt = blockIdx.x;
    int b = bt >> 6, t = bt & 63;
    int tok = (t == 0) ? 1 : targets[b * NT + t - 1];
    const float4* s = (const float4*)(E + (size_t)tok * ND);
    float4* d = (float4*)(emb + (size_t)bt * ND);
    d[threadIdx.x] = s[threadIdx.x];   // 128 threads * 16B = 512 floats
}

// ---------------- generic split-bf16 GEMM: C[M][N] = A[M][K] @ B[N][K]^T + bias ----------------
// 3-term emulation: Ahi*Bhi + Alo*Bhi + Ahi*Blo  (error ~2^-18 relative)
// BM=BN=128, BK=64, 256 threads = 4 waves (2x2 of 64x64), 16x16x32 bf16 MFMA.
template<bool ARGMAX>
__global__ __launch_bounds__(256, 2) void k_gemm(
    const float* __restrict__ A,    // [M][K] row-major
    const float* __restrict__ Bm,   // [N][K] row-major
    const float* __restrict__ bias1,
    const float* __restrict__ bias2,
    float* __restrict__ C,          // [M][N]
    u64* __restrict__ argm,
    int M, int N, int K, int NB) {
    __shared__ u16 sAh[128 * 64], sAl[128 * 64], sBh[128 * 64], sBl[128 * 64];
    int tid = threadIdx.x, lane = tid & 63, w = tid >> 6;
    int wm = w >> 1, wn = w & 1;

    // XCD-affinity swizzle: the 8 m-blocks sharing one n-slice land on the same XCD
    int bid = blockIdx.x;
    int full = NB >> 3;
    int thresh = full << 6;
    int m_idx, n_idx;
    if (bid < thresh) {
        int g = bid >> 6, r = bid & 63;
        n_idx = g * 8 + (r & 7);
        m_idx = r >> 3;
    } else {
        int r2 = bid - thresh;
        int nrem = NB - (full << 3);
        n_idx = (full << 3) + r2 % nrem;
        m_idx = r2 / nrem;
    }
    int mbase = m_idx * 128, nbase = n_idx * 128;

    f32x4 acc[4][4];
    #pragma unroll
    for (int i = 0; i < 4; ++i)
        #pragma unroll
        for (int j = 0; j < 4; ++j) acc[i][j] = (f32x4){0.f, 0.f, 0.f, 0.f};

    const int lc = lane & 15, lk4 = lane >> 4;

    #pragma unroll 1
    for (int kc = 0; kc < K; kc += 64) {
        // -------- stage A & B chunk: fp32 -> bf16 hi/lo into swizzled LDS --------
        #pragma unroll
        for (int it = 0; it < 4; ++it) {
            int gi = tid + it * 256;          // 0..1023
            int row = gi >> 3, gin = gi & 7;  // 128 rows x 8 granules(8 elems)
            int gs8 = ((gin ^ (row & 7)) << 3);
            {
                const float* src = A + (size_t)(mbase + row) * K + kc + gin * 8;
                float4 f0 = *(const float4*)(src);
                float4 f1 = *(const float4*)(src + 4);
                float fv[8] = {f0.x, f0.y, f0.z, f0.w, f1.x, f1.y, f1.z, f1.w};
                short8 h8, l8;
                #pragma unroll
                for (int e = 0; e < 8; ++e) {
                    u16 hi = f2bf(fv[e]);
                    h8[e] = (short)hi;
                    l8[e] = (short)f2bf(fv[e] - bf2f(hi));
                }
                *(short8*)&sAh[row * 64 + gs8] = h8;
                *(short8*)&sAl[row * 64 + gs8] = l8;
            }
            {
                int n = nbase + row;
                short8 h8, l8;
                if (n < N) {
                    const float* src = Bm + (size_t)n * K + kc + gin * 8;
                    float4 f0 = *(const float4*)(src);
                    float4 f1 = *(const float4*)(src + 4);
                    float fv[8] = {f0.x, f0.y, f0.z, f0.w, f1.x, f1.y, f1.z, f1.w};
                    #pragma unroll
                    for (int e = 0; e < 8; ++e) {
                        u16 hi = f2bf(fv[e]);
                        h8[e] = (short)hi;
                        l8[e] = (short)f2bf(fv[e] - bf2f(hi));
                    }
                } else {
                    #pragma unroll
                    for (int e = 0; e < 8; ++e) { h8[e] = 0; l8[e] = 0; }
                }
                *(short8*)&sBh[row * 64 + gs8] = h8;
                *(short8*)&sBl[row * 64 + gs8] = l8;
            }
        }
        __syncthreads();
        // -------- MFMA on the chunk --------
        #pragma unroll
        for (int ks = 0; ks < 2; ++ks) {
            short8 ah[4], al[4], bh[4], bl[4];
            #pragma unroll
            for (int mi = 0; mi < 4; ++mi) {
                int r = wm * 64 + mi * 16 + lc;
                int gs8 = (((ks * 4 + lk4) ^ (r & 7)) << 3);
                ah[mi] = *(const short8*)&sAh[r * 64 + gs8];
                al[mi] = *(const short8*)&sAl[r * 64 + gs8];
            }
            #pragma unroll
            for (int ni = 0; ni < 4; ++ni) {
                int r = wn * 64 + ni * 16 + lc;
                int gs8 = (((ks * 4 + lk4) ^ (r & 7)) << 3);
                bh[ni] = *(const short8*)&sBh[r * 64 + gs8];
                bl[ni] = *(const short8*)&sBl[r * 64 + gs8];
            }
            #pragma unroll
            for (int mi = 0; mi < 4; ++mi)
                #pragma unroll
                for (int ni = 0; ni < 4; ++ni) {
                    acc[mi][ni] = __builtin_amdgcn_mfma_f32_16x16x32_bf16(ah[mi], bh[ni], acc[mi][ni], 0, 0, 0);
                    acc[mi][ni] = __builtin_amdgcn_mfma_f32_16x16x32_bf16(al[mi], bh[ni], acc[mi][ni], 0, 0, 0);
                    acc[mi][ni] = __builtin_amdgcn_mfma_f32_16x16x32_bf16(ah[mi], bl[ni], acc[mi][ni], 0, 0, 0);
                }
        }
        __syncthreads();
    }

    // -------- epilogue: bias, store, fused argmax --------
    float bsum[4];
    int cols[4];
    #pragma unroll
    for (int ni = 0; ni < 4; ++ni) {
        int col = nbase + wn * 64 + ni * 16 + lc;
        cols[ni] = col;
        float bv = 0.f;
        if (col < N) { bv = bias1[col]; if (bias2) bv += bias2[col]; }
        bsum[ni] = bv;
    }
    #pragma unroll
    for (int mi = 0; mi < 4; ++mi) {
        #pragma unroll
        for (int r_ = 0; r_ < 4; ++r_) {
            int row = mbase + wm * 64 + mi * 16 + (lk4 << 2) + r_;   // m89 C/D layout
            float* crow = C + (size_t)row * N;
            u64 best = 0ull;
            #pragma unroll
            for (int ni = 0; ni < 4; ++ni) {
                if (cols[ni] < N) {
                    float v = acc[mi][ni][r_] + bsum[ni];
                    crow[cols[ni]] = v;
                    if (ARGMAX) {
                        u32 bits = __builtin_bit_cast(u32, v);
                        u32 mono = (bits & 0x80000000u) ? ~bits : (bits | 0x80000000u);
                        u64 p = ((u64)mono << 32) | (u64)(0xFFFFFFFFu - (u32)cols[ni]);
                        best = best > p ? best : p;
                    }
                }
            }
            if (ARGMAX) {
                #pragma unroll
                for (int s = 1; s < 16; s <<= 1) {
                    u64 o = __shfl_xor((unsigned long long)best, s, 64);
                    best = best > o ? best : o;
                }
                if (lc == 0) atomicMax(&argm[row], best);
            }
        }
    }
}

// ---------------- K4: LSTM recurrence, one block per batch element ----------------
// 512 threads = 8 waves; gates via M=1-in-16 MFMA (A rows replicated with h),
// B-fragments are 16B-contiguous K-slices loaded directly from pre-split W_hh.
__global__ __launch_bounds__(512, 2) void k_lstm(
    const float* __restrict__ xg, const float* __restrict__ h0,
    const u16* __restrict__ Whi, const u16* __restrict__ Wlo,
    float* __restrict__ hs) {
    __shared__ u16 hhi[NH], hlo[NH];
    __shared__ float g_lds[NG];
    int b = blockIdx.x, tid = threadIdx.x;
    int lane = tid & 63, w = tid >> 6;   // 8 waves
    float c = 0.f;
    {
        float h = h0[b * NH + tid];
        u16 hi = f2bf(h);
        hhi[tid] = hi;
        hlo[tid] = f2bf(h - bf2f(hi));
    }
    __syncthreads();
    const int n0 = w * 256;                       // 16 n-tiles of 16 per wave
    const int lc = lane & 15, lk = (lane >> 4) << 3;
    #pragma unroll 1
    for (int t = 0; t < NT; ++t) {
        f32x4 acc[16];
        #pragma unroll
        for (int j = 0; j < 16; ++j) acc[j] = (f32x4){0.f, 0.f, 0.f, 0.f};
        #pragma unroll 1
        for (int kk = 0; kk < 16; ++kk) {
            int k = kk * 32 + lk;
            short8 ah = *(const short8*)&hhi[k];   // broadcast h slice -> all A rows
            short8 al = *(const short8*)&hlo[k];
            #pragma unroll
            for (int j = 0; j < 16; ++j) {
                size_t off = (size_t)(n0 + j * 16 + lc) * NH + k;
                short8 bh = *(const short8*)&Whi[off];
                short8 bl = *(const short8*)&Wlo[off];
                acc[j] = __builtin_amdgcn_mfma_f32_16x16x32_bf16(ah, bh, acc[j], 0, 0, 0);
                acc[j] = __builtin_amdgcn_mfma_f32_16x16x32_bf16(al, bh, acc[j], 0, 0, 0);
                acc[j] = __builtin_amdgcn_mfma_f32_16x16x32_bf16(ah, bl, acc[j], 0, 0, 0);
            }
        }
        const float* xrow = xg + (size_t)(b * NT + t) * NG;
        if (lane < 16) {
            #pragma unroll
            for (int j = 0; j < 16; ++j) {
                int n = n0 + j * 16 + lane;
                g_lds[n] = acc[j][0] + xrow[n];    // rows replicated -> reg 0
            }
        }
        __syncthreads();
        {
            float gi_ = g_lds[tid];
            float gf_ = g_lds[NH + tid];
            float gg_ = g_lds[2 * NH + tid];
            float go_ = g_lds[3 * NH + tid];
            c = sigm(gf_) * c + sigm(gi_) * tanhf(gg_);
            float h = sigm(go_) * tanhf(c);
            hs[(size_t)(b * NT + t) * NH + tid] = h;
            u16 hi = f2bf(h);
            hhi[tid] = hi;
            hlo[tid] = f2bf(h - bf2f(hi));
        }
        __syncthreads();
    }
}

// ---------------- K6: decode packed argmax -> float predictions ----------------
__global__ void k_decode(const u64* __restrict__ argm, float* __restrict__ pred) {
    int i = blockIdx.x * 256 + threadIdx.x;
    if (i < NB_B * NT) {
        u32 enc = (u32)(argm[i] & 0xFFFFFFFFull);
        pred[i] = (float)(0xFFFFFFFFu - enc);
    }
}

extern "C" void kernel_launch(void* const* d_in, const int* in_sizes, int n_in,
                              void* d_out, int out_size, void* d_ws, size_t ws_size,
                              hipStream_t stream) {
    const float* sh  = (const float*)d_in[0];
    const float* oh  = (const float*)d_in[1];
    const int*   tg  = (const int*)d_in[2];
    const float* Wc  = (const float*)d_in[3];
    const float* bc  = (const float*)d_in[4];
    const float* E   = (const float*)d_in[5];
    const float* Wih = (const float*)d_in[6];
    const float* Whh = (const float*)d_in[7];
    const float* bih = (const float*)d_in[8];
    const float* bhh = (const float*)d_in[9];
    const float* Wo  = (const float*)d_in[10];
    const float* bo  = (const float*)d_in[11];

    float* out_logits = (float*)d_out;
    float* out_pred   = out_logits + (size_t)NB_B * NT * NV;
    float* out_rep    = out_pred + NB_B * NT;

    char* ws = (char*)d_ws;
    u16*   Whi  = (u16*)(ws);                                   // 2 MB
    u16*   Wlo  = (u16*)(ws + (size_t)2  * 1024 * 1024);        // 2 MB
    float* emb  = (float*)(ws + (size_t)4  * 1024 * 1024);      // 2 MB
    float* xg   = (float*)(ws + (size_t)6  * 1024 * 1024);      // 8 MB
    float* hs   = (float*)(ws + (size_t)14 * 1024 * 1024);      // 2 MB
    float* h0   = (float*)(ws + (size_t)16 * 1024 * 1024);      // 32 KB
    u64*   argm = (u64*)(ws + (size_t)16 * 1024 * 1024 + 32 * 1024); // 8 KB

    k_prep<<<dim3(4096), dim3(256), 0, stream>>>(Whh, Whi, Wlo, argm);
    k_combine<<<dim3(NB_B), dim3(256), 0, stream>>>(sh, oh, Wc, bc, h0, out_rep);
    k_gather<<<dim3(NB_B * NT), dim3(128), 0, stream>>>(tg, E, emb);
    // xg = emb @ W_ih^T + b_ih + b_hh   (M=1024, N=2048, K=512, NB=16)
    k_gemm<false><<<dim3(8 * 16), dim3(256), 0, stream>>>(
        emb, Wih, bih, bhh, xg, (u64*)nullptr, NB_B * NT, NG, ND, 16);
    k_lstm<<<dim3(NB_B), dim3(512), 0, stream>>>(xg, h0, Whi, Wlo, hs);
    // logits = hs @ Wo^T + bo, fused argmax  (M=1024, N=50257, K=512, NB=393)
    k_gemm<true><<<dim3(8 * 393), dim3(256), 0, stream>>>(
        hs, Wo, bo, (const float*)nullptr, out_logits, argm, NB_B * NT, NV, NH, 393);
    k_decode<<<dim3(4), dim3(256), 0, stream>>>(argm, out_pred);
}

// Round 2
// 1396.125 us; speedup vs baseline: 5.7075x; 5.7075x over previous
//
#include <hip/hip_runtime.h>
#include <cstdint>
#include <cstddef>

typedef unsigned short u16;
typedef unsigned int   u32;
typedef unsigned long long u64;

typedef __attribute__((ext_vector_type(8))) short short8;
typedef __attribute__((ext_vector_type(4))) float f32x4;

#define NB_B 16
#define NT   64
#define NH   512
#define ND   512
#define NV   50257
#define NG   2048   // 4*H
#define LSTM_NBLK 32
#define UPB  16     // hidden units per LSTM block

__device__ __forceinline__ u16 f2bf(float f) {
    u32 u = __builtin_bit_cast(u32, f);
    return (u16)((u + 0x7FFFu + ((u >> 16) & 1u)) >> 16);   // RNE to bf16
}
__device__ __forceinline__ float bf2f(u16 h) {
    return __builtin_bit_cast(float, (u32)h << 16);
}
__device__ __forceinline__ float sigm(float x) { return 1.0f / (1.0f + expf(-x)); }

// ---------------- K0: split W_hh -> bf16 hi/lo, zero argmax + sync slots ----------------
__global__ void k_prep(const float* __restrict__ Whh, u16* __restrict__ Whi,
                       u16* __restrict__ Wlo, u64* __restrict__ argm,
                       u32* __restrict__ cnt) {
    int i = blockIdx.x * 256 + threadIdx.x;
    if (i < NG * NH) {
        float f = Whh[i];
        u16 hi = f2bf(f);
        Whi[i] = hi;
        Wlo[i] = f2bf(f - bf2f(hi));
    }
    if (i < NB_B * NT) argm[i] = 0ull;
    if (i < NT) cnt[i] = 0u;
}

// ---------------- K1: combine = relu(concat(sh,oh) @ Wc^T + bc) ----------------
__global__ __launch_bounds__(256) void k_combine(
    const float* __restrict__ sh, const float* __restrict__ oh,
    const float* __restrict__ Wc, const float* __restrict__ bc,
    float* __restrict__ h0, float* __restrict__ rep_out) {
    __shared__ float x[1024];
    int b = blockIdx.x, tid = threadIdx.x;
    for (int i = tid; i < 1024; i += 256)
        x[i] = (i < NH) ? sh[b * NH + i] : oh[b * NH + i - NH];
    __syncthreads();
    for (int n = tid; n < NH; n += 256) {
        const float* wr = Wc + (size_t)n * 1024;
        float s = 0.f;
        #pragma unroll 4
        for (int k = 0; k < 1024; k += 4) {
            float4 w = *(const float4*)(wr + k);
            s += x[k] * w.x + x[k+1] * w.y + x[k+2] * w.z + x[k+3] * w.w;
        }
        s += bc[n];
        s = fmaxf(s, 0.f);
        h0[b * NH + n] = s;
        rep_out[b * NH + n] = s;
    }
}

// ---------------- K2: gather embedding rows (teacher forcing, BOS=1) ----------------
__global__ void k_gather(const int* __restrict__ targets, const float* __restrict__ E,
                         float* __restrict__ emb) {
    int bt = blockIdx.x;
    int b = bt >> 6, t = bt & 63;
    int tok = (t == 0) ? 1 : targets[b * NT + t - 1];
    const float4* s = (const float4*)(E + (size_t)tok * ND);
    float4* d = (float4*)(emb + (size_t)bt * ND);
    d[threadIdx.x] = s[threadIdx.x];   // 128 threads * 16B = 512 floats
}

// ---------------- generic split-bf16 GEMM: C[M][N] = A[M][K] @ B[N][K]^T + bias ----------------
// 3-term emulation: Ahi*Bhi + Alo*Bhi + Ahi*Blo  (error ~2^-18 relative)
// BM=BN=128, BK=64, 256 threads = 4 waves (2x2 of 64x64), 16x16x32 bf16 MFMA.
template<bool ARGMAX>
__global__ __launch_bounds__(256, 2) void k_gemm(
    const float* __restrict__ A,    // [M][K] row-major
    const float* __restrict__ Bm,   // [N][K] row-major
    const float* __restrict__ bias1,
    const float* __restrict__ bias2,
    float* __restrict__ C,          // [M][N]
    u64* __restrict__ argm,
    int M, int N, int K, int NB) {
    __shared__ u16 sAh[128 * 64], sAl[128 * 64], sBh[128 * 64], sBl[128 * 64];
    int tid = threadIdx.x, lane = tid & 63, w = tid >> 6;
    int wm = w >> 1, wn = w & 1;

    // XCD-affinity swizzle: the 8 m-blocks sharing one n-slice land on the same XCD
    int bid = blockIdx.x;
    int full = NB >> 3;
    int thresh = full << 6;
    int m_idx, n_idx;
    if (bid < thresh) {
        int g = bid >> 6, r = bid & 63;
        n_idx = g * 8 + (r & 7);
        m_idx = r >> 3;
    } else {
        int r2 = bid - thresh;
        int nrem = NB - (full << 3);
        n_idx = (full << 3) + r2 % nrem;
        m_idx = r2 / nrem;
    }
    int mbase = m_idx * 128, nbase = n_idx * 128;

    f32x4 acc[4][4];
    #pragma unroll
    for (int i = 0; i < 4; ++i)
        #pragma unroll
        for (int j = 0; j < 4; ++j) acc[i][j] = (f32x4){0.f, 0.f, 0.f, 0.f};

    const int lc = lane & 15, lk4 = lane >> 4;

    #pragma unroll 1
    for (int kc = 0; kc < K; kc += 64) {
        // -------- stage A & B chunk: fp32 -> bf16 hi/lo into swizzled LDS --------
        #pragma unroll
        for (int it = 0; it < 4; ++it) {
            int gi = tid + it * 256;          // 0..1023
            int row = gi >> 3, gin = gi & 7;  // 128 rows x 8 granules(8 elems)
            int gs8 = ((gin ^ (row & 7)) << 3);
            {
                const float* src = A + (size_t)(mbase + row) * K + kc + gin * 8;
                float4 f0 = *(const float4*)(src);
                float4 f1 = *(const float4*)(src + 4);
                float fv[8] = {f0.x, f0.y, f0.z, f0.w, f1.x, f1.y, f1.z, f1.w};
                short8 h8, l8;
                #pragma unroll
                for (int e = 0; e < 8; ++e) {
                    u16 hi = f2bf(fv[e]);
                    h8[e] = (short)hi;
                    l8[e] = (short)f2bf(fv[e] - bf2f(hi));
                }
                *(short8*)&sAh[row * 64 + gs8] = h8;
                *(short8*)&sAl[row * 64 + gs8] = l8;
            }
            {
                int n = nbase + row;
                short8 h8, l8;
                if (n < N) {
                    const float* src = Bm + (size_t)n * K + kc + gin * 8;
                    float4 f0 = *(const float4*)(src);
                    float4 f1 = *(const float4*)(src + 4);
                    float fv[8] = {f0.x, f0.y, f0.z, f0.w, f1.x, f1.y, f1.z, f1.w};
                    #pragma unroll
                    for (int e = 0; e < 8; ++e) {
                        u16 hi = f2bf(fv[e]);
                        h8[e] = (short)hi;
                        l8[e] = (short)f2bf(fv[e] - bf2f(hi));
                    }
                } else {
                    #pragma unroll
                    for (int e = 0; e < 8; ++e) { h8[e] = 0; l8[e] = 0; }
                }
                *(short8*)&sBh[row * 64 + gs8] = h8;
                *(short8*)&sBl[row * 64 + gs8] = l8;
            }
        }
        __syncthreads();
        // -------- MFMA on the chunk --------
        #pragma unroll
        for (int ks = 0; ks < 2; ++ks) {
            short8 ah[4], al[4], bh[4], bl[4];
            #pragma unroll
            for (int mi = 0; mi < 4; ++mi) {
                int r = wm * 64 + mi * 16 + lc;
                int gs8 = (((ks * 4 + lk4) ^ (r & 7)) << 3);
                ah[mi] = *(const short8*)&sAh[r * 64 + gs8];
                al[mi] = *(const short8*)&sAl[r * 64 + gs8];
            }
            #pragma unroll
            for (int ni = 0; ni < 4; ++ni) {
                int r = wn * 64 + ni * 16 + lc;
                int gs8 = (((ks * 4 + lk4) ^ (r & 7)) << 3);
                bh[ni] = *(const short8*)&sBh[r * 64 + gs8];
                bl[ni] = *(const short8*)&sBl[r * 64 + gs8];
            }
            #pragma unroll
            for (int mi = 0; mi < 4; ++mi)
                #pragma unroll
                for (int ni = 0; ni < 4; ++ni) {
                    acc[mi][ni] = __builtin_amdgcn_mfma_f32_16x16x32_bf16(ah[mi], bh[ni], acc[mi][ni], 0, 0, 0);
                    acc[mi][ni] = __builtin_amdgcn_mfma_f32_16x16x32_bf16(al[mi], bh[ni], acc[mi][ni], 0, 0, 0);
                    acc[mi][ni] = __builtin_amdgcn_mfma_f32_16x16x32_bf16(ah[mi], bl[ni], acc[mi][ni], 0, 0, 0);
                }
        }
        __syncthreads();
    }

    // -------- epilogue: bias, store, fused argmax --------
    float bsum[4];
    int cols[4];
    #pragma unroll
    for (int ni = 0; ni < 4; ++ni) {
        int col = nbase + wn * 64 + ni * 16 + lc;
        cols[ni] = col;
        float bv = 0.f;
        if (col < N) { bv = bias1[col]; if (bias2) bv += bias2[col]; }
        bsum[ni] = bv;
    }
    #pragma unroll
    for (int mi = 0; mi < 4; ++mi) {
        #pragma unroll
        for (int r_ = 0; r_ < 4; ++r_) {
            int row = mbase + wm * 64 + mi * 16 + (lk4 << 2) + r_;   // m89 C/D layout
            float* crow = C + (size_t)row * N;
            u64 best = 0ull;
            #pragma unroll
            for (int ni = 0; ni < 4; ++ni) {
                if (cols[ni] < N) {
                    float v = acc[mi][ni][r_] + bsum[ni];
                    crow[cols[ni]] = v;
                    if (ARGMAX) {
                        u32 bits = __builtin_bit_cast(u32, v);
                        u32 mono = (bits & 0x80000000u) ? ~bits : (bits | 0x80000000u);
                        u64 p = ((u64)mono << 32) | (u64)(0xFFFFFFFFu - (u32)cols[ni]);
                        best = best > p ? best : p;
                    }
                }
            }
            if (ARGMAX) {
                #pragma unroll
                for (int s = 1; s < 16; s <<= 1) {
                    u64 o = __shfl_xor((unsigned long long)best, s, 64);
                    best = best > o ? best : o;
                }
                if (lc == 0) atomicMax(&argm[row], best);
            }
        }
    }
}

// ---------------- K4: LSTM, weight-stationary, 32 blocks x 16 hidden units ----------------
// Each block owns 64 gate rows (4 gates x 16 units) held in REGISTERS (hi/lo short8[16]).
// M=16 batches in one MFMA tile. Per-step h broadcast via double-buffered global
// packed-u32 buffers + device-scope counter barrier (agent atomics; XCD-safe).
__global__ __launch_bounds__(256, 1) void k_lstm(
    const float* __restrict__ xg, const float* __restrict__ h0,
    const u16* __restrict__ Whi, const u16* __restrict__ Wlo,
    float* __restrict__ hs,
    u32* __restrict__ Ghi, u32* __restrict__ Glo,   // [2][16*256] packed (lo16=even elem)
    u32* __restrict__ cnt) {                        // [NT]
    __shared__ u16 hhi[16 * 512];     // [batch][k], granule-XOR swizzled
    __shared__ u16 hlo[16 * 512];
    __shared__ float g_lds[4 * 256];  // [gate][batch*16+unit]

    const int tid = threadIdx.x;
    const int lane = tid & 63, w = tid >> 6;       // wave = gate type (i,f,g,o)
    const int blk = blockIdx.x;
    const int u0 = blk * UPB;
    const int lc = lane & 15, lk4 = lane >> 4;
    const int bown = tid >> 4, uown = tid & 15;    // owned (batch, unit)

    // ---- weights -> registers (once) ----
    short8 bh[16], bl[16];
    {
        size_t base = (size_t)(w * NH + u0 + lc) * NH + lk4 * 8;
        #pragma unroll
        for (int kk = 0; kk < 16; ++kk) {
            bh[kk] = *(const short8*)(Whi + base + kk * 32);
            bl[kk] = *(const short8*)(Wlo + base + kk * 32);
        }
    }

    // ---- stage h0 -> LDS (fp32 -> hi/lo, swizzled) ----
    #pragma unroll
    for (int i = 0; i < 32; ++i) {
        int idx = i * 256 + tid;           // 0..8191
        int b = idx >> 9, k = idx & 511;
        float f = h0[b * NH + k];
        u16 hi = f2bf(f), lo = f2bf(f - bf2f(hi));
        int g = k >> 3;
        int ea = b * 512 + ((g ^ (b & 7)) << 3) + (k & 7);
        hhi[ea] = hi;
        hlo[ea] = lo;
    }
    float c = 0.f;
    __syncthreads();

    #pragma unroll 1
    for (int t = 0; t < NT; ++t) {
        // ---- gates = h @ W^T via 3-term split MFMA (3 independent acc chains) ----
        f32x4 a0 = (f32x4){0.f,0.f,0.f,0.f};
        f32x4 a1 = (f32x4){0.f,0.f,0.f,0.f};
        f32x4 a2 = (f32x4){0.f,0.f,0.f,0.f};
        #pragma unroll
        for (int kk = 0; kk < 16; ++kk) {
            int g = kk * 4 + lk4;
            int ea = lc * 512 + ((g ^ (lc & 7)) << 3);
            short8 ah = *(const short8*)&hhi[ea];
            short8 al = *(const short8*)&hlo[ea];
            a0 = __builtin_amdgcn_mfma_f32_16x16x32_bf16(ah, bh[kk], a0, 0, 0, 0);
            a1 = __builtin_amdgcn_mfma_f32_16x16x32_bf16(al, bh[kk], a1, 0, 0, 0);
            a2 = __builtin_amdgcn_mfma_f32_16x16x32_bf16(ah, bl[kk], a2, 0, 0, 0);
        }
        // D[batch = lk4*4+r][unit = lc] for gate w
        #pragma unroll
        for (int r = 0; r < 4; ++r)
            g_lds[w * 256 + (lk4 * 4 + r) * 16 + lc] = a0[r] + a1[r] + a2[r];
        __syncthreads();

        // ---- per-(batch,unit) nonlinearity; thread owns one pair ----
        const float* xrow = xg + (size_t)(bown * NT + t) * NG + u0 + uown;
        float gi = g_lds[0 * 256 + tid] + xrow[0];
        float gf = g_lds[1 * 256 + tid] + xrow[NH];
        float gg = g_lds[2 * 256 + tid] + xrow[2 * NH];
        float go = g_lds[3 * 256 + tid] + xrow[3 * NH];
        c = sigm(gf) * c + sigm(gi) * tanhf(gg);
        float h = sigm(go) * tanhf(c);
        hs[(size_t)(bown * NT + t) * NH + u0 + uown] = h;

        if (t < NT - 1) {
            u16 hi = f2bf(h), lo = f2bf(h - bf2f(hi));
            // pair adjacent units -> packed u32, publish (relaxed agent atomics)
            u32 ohi = (u32)(u16)__shfl_xor((int)(u32)hi, 1, 64);
            u32 olo = (u32)(u16)__shfl_xor((int)(u32)lo, 1, 64);
            int buf = (t & 1) * 4096;
            if ((tid & 1) == 0) {
                int word = bown * 256 + ((u0 + uown) >> 1);
                __hip_atomic_store(&Ghi[buf + word], (u32)hi | (ohi << 16),
                                   __ATOMIC_RELAXED, __HIP_MEMORY_SCOPE_AGENT);
                __hip_atomic_store(&Glo[buf + word], (u32)lo | (olo << 16),
                                   __ATOMIC_RELAXED, __HIP_MEMORY_SCOPE_AGENT);
            }
            __threadfence();              // make stores agent-visible
            __syncthreads();              // all threads' fences done
            if (tid == 0) {
                __hip_atomic_fetch_add(&cnt[t], 1u, __ATOMIC_RELEASE, __HIP_MEMORY_SCOPE_AGENT);
                while (__hip_atomic_load(&cnt[t], __ATOMIC_ACQUIRE, __HIP_MEMORY_SCOPE_AGENT) < LSTM_NBLK) {}
            }
            __syncthreads();
            // ---- stage new h -> LDS (coalesced agent loads, swizzled ds_write) ----
            #pragma unroll
            for (int i = 0; i < 16; ++i) {
                int word = i * 256 + tid;       // b = i, k2 = tid  (b*256 + k2)
                int b = word >> 8, k2 = word & 255;
                u32 vh = __hip_atomic_load(&Ghi[buf + word], __ATOMIC_RELAXED, __HIP_MEMORY_SCOPE_AGENT);
                u32 vl = __hip_atomic_load(&Glo[buf + word], __ATOMIC_RELAXED, __HIP_MEMORY_SCOPE_AGENT);
                int k = k2 * 2, g = k >> 3;
                int ea = b * 512 + ((g ^ (b & 7)) << 3) + (k & 7);
                *(u32*)&hhi[ea] = vh;
                *(u32*)&hlo[ea] = vl;
            }
            __syncthreads();
        }
    }
}

// ---------------- K6: decode packed argmax -> float predictions ----------------
__global__ void k_decode(const u64* __restrict__ argm, float* __restrict__ pred) {
    int i = blockIdx.x * 256 + threadIdx.x;
    if (i < NB_B * NT) {
        u32 enc = (u32)(argm[i] & 0xFFFFFFFFull);
        pred[i] = (float)(0xFFFFFFFFu - enc);
    }
}

extern "C" void kernel_launch(void* const* d_in, const int* in_sizes, int n_in,
                              void* d_out, int out_size, void* d_ws, size_t ws_size,
                              hipStream_t stream) {
    const float* sh  = (const float*)d_in[0];
    const float* oh  = (const float*)d_in[1];
    const int*   tg  = (const int*)d_in[2];
    const float* Wc  = (const float*)d_in[3];
    const float* bc  = (const float*)d_in[4];
    const float* E   = (const float*)d_in[5];
    const float* Wih = (const float*)d_in[6];
    const float* Whh = (const float*)d_in[7];
    const float* bih = (const float*)d_in[8];
    const float* bhh = (const float*)d_in[9];
    const float* Wo  = (const float*)d_in[10];
    const float* bo  = (const float*)d_in[11];

    float* out_logits = (float*)d_out;
    float* out_pred   = out_logits + (size_t)NB_B * NT * NV;
    float* out_rep    = out_pred + NB_B * NT;

    char* ws = (char*)d_ws;
    u16*   Whi  = (u16*)(ws);                                   // 2 MB
    u16*   Wlo  = (u16*)(ws + (size_t)2  * 1024 * 1024);        // 2 MB
    float* emb  = (float*)(ws + (size_t)4  * 1024 * 1024);      // 2 MB
    float* xg   = (float*)(ws + (size_t)6  * 1024 * 1024);      // 8 MB
    float* hs   = (float*)(ws + (size_t)14 * 1024 * 1024);      // 2 MB
    float* h0   = (float*)(ws + (size_t)16 * 1024 * 1024);      // 32 KB
    u64*   argm = (u64*)(ws + (size_t)16 * 1024 * 1024 + 32 * 1024);   // 8 KB
    u32*   Ghi  = (u32*)(ws + (size_t)16 * 1024 * 1024 + 40 * 1024);   // 32 KB
    u32*   Glo  = (u32*)(ws + (size_t)16 * 1024 * 1024 + 72 * 1024);   // 32 KB
    u32*   cnt  = (u32*)(ws + (size_t)16 * 1024 * 1024 + 104 * 1024);  // 256 B

    k_prep<<<dim3(4096), dim3(256), 0, stream>>>(Whh, Whi, Wlo, argm, cnt);
    k_combine<<<dim3(NB_B), dim3(256), 0, stream>>>(sh, oh, Wc, bc, h0, out_rep);
    k_gather<<<dim3(NB_B * NT), dim3(128), 0, stream>>>(tg, E, emb);
    // xg = emb @ W_ih^T + b_ih + b_hh   (M=1024, N=2048, K=512, NB=16)
    k_gemm<false><<<dim3(8 * 16), dim3(256), 0, stream>>>(
        emb, Wih, bih, bhh, xg, (u64*)nullptr, NB_B * NT, NG, ND, 16);
    k_lstm<<<dim3(LSTM_NBLK), dim3(256), 0, stream>>>(xg, h0, Whi, Wlo, hs, Ghi, Glo, cnt);
    // logits = hs @ Wo^T + bo, fused argmax  (M=1024, N=50257, K=512, NB=393)
    k_gemm<true><<<dim3(8 * 393), dim3(256), 0, stream>>>(
        hs, Wo, bo, (const float*)nullptr, out_logits, argm, NB_B * NT, NV, NH, 393);
    k_decode<<<dim3(4), dim3(256), 0, stream>>>(argm, out_pred);
}

// Round 6
// 1219.805 us; speedup vs baseline: 6.5326x; 1.1445x over previous
//
#include <hip/hip_runtime.h>
#include <hip/hip_bf16.h>
#include <cstdint>
#include <cstddef>

typedef unsigned short u16;
typedef unsigned int   u32;
typedef unsigned long long u64;

typedef __attribute__((ext_vector_type(8))) short short8;
typedef __attribute__((ext_vector_type(4))) float f32x4;

#define NB_B 16
#define NT   64
#define NH   512
#define ND   512
#define NV   50257
#define NG   2048   // 4*H
#define LSTM_NBLK 32
#define UPB  16     // hidden units per LSTM block

__device__ __forceinline__ u16 f2bf(float f) {
    __hip_bfloat16 b = __float2bfloat16(f);      // HW RNE convert
    return __builtin_bit_cast(u16, b);
}
__device__ __forceinline__ float bf2f(u16 h) {
    return __builtin_bit_cast(float, (u32)h << 16);
}
__device__ __forceinline__ float sigm(float x) { return 1.0f / (1.0f + expf(-x)); }

// ---------------- K0: split W_hh -> bf16 hi/lo, zero argmax + flag slots ----------------
__global__ void k_prep(const float* __restrict__ Whh, u16* __restrict__ Whi,
                       u16* __restrict__ Wlo, u64* __restrict__ argm,
                       u32* __restrict__ flags) {
    int i = blockIdx.x * 256 + threadIdx.x;
    if (i < NG * NH) {
        float f = Whh[i];
        u16 hi = f2bf(f);
        Whi[i] = hi;
        Wlo[i] = f2bf(f - bf2f(hi));
    }
    if (i < NB_B * NT) argm[i] = 0ull;
    if (i < NT * LSTM_NBLK) flags[i] = 0u;
}

// ---------------- K0b: pre-split Wo -> packed (hi<<16)|lo u32 ----------------
__global__ void k_pack_wo(const float* __restrict__ Wo, u32* __restrict__ Wo_pk) {
    size_t base = ((size_t)blockIdx.x * 256 + threadIdx.x) * 8;
    if (base >= (size_t)NV * NH) return;
    float4 f0 = *(const float4*)(Wo + base);
    float4 f1 = *(const float4*)(Wo + base + 4);
    float fv[8] = {f0.x, f0.y, f0.z, f0.w, f1.x, f1.y, f1.z, f1.w};
    u32 ov[8];
    #pragma unroll
    for (int e = 0; e < 8; ++e) {
        u16 hi = f2bf(fv[e]);
        u16 lo = f2bf(fv[e] - bf2f(hi));
        ov[e] = ((u32)hi << 16) | (u32)lo;
    }
    *(uint4*)(Wo_pk + base) = (uint4){ov[0], ov[1], ov[2], ov[3]};
    *(uint4*)(Wo_pk + base + 4) = (uint4){ov[4], ov[5], ov[6], ov[7]};
}

// ---------------- K1: combine = relu(concat(sh,oh) @ Wc^T + bc) ----------------
__global__ __launch_bounds__(256) void k_combine(
    const float* __restrict__ sh, const float* __restrict__ oh,
    const float* __restrict__ Wc, const float* __restrict__ bc,
    float* __restrict__ h0, float* __restrict__ rep_out) {
    __shared__ float x[1024];
    int b = blockIdx.x, tid = threadIdx.x;
    for (int i = tid; i < 1024; i += 256)
        x[i] = (i < NH) ? sh[b * NH + i] : oh[b * NH + i - NH];
    __syncthreads();
    for (int n = tid; n < NH; n += 256) {
        const float* wr = Wc + (size_t)n * 1024;
        float s = 0.f;
        #pragma unroll 4
        for (int k = 0; k < 1024; k += 4) {
            float4 w = *(const float4*)(wr + k);
            s += x[k] * w.x + x[k+1] * w.y + x[k+2] * w.z + x[k+3] * w.w;
        }
        s += bc[n];
        s = fmaxf(s, 0.f);
        h0[b * NH + n] = s;
        rep_out[b * NH + n] = s;
    }
}

// ---------------- K2: gather embedding rows (teacher forcing, BOS=1) ----------------
__global__ void k_gather(const int* __restrict__ targets, const float* __restrict__ E,
                         float* __restrict__ emb) {
    int bt = blockIdx.x;
    int b = bt >> 6, t = bt & 63;
    int tok = (t == 0) ? 1 : targets[b * NT + t - 1];
    const float4* s = (const float4*)(E + (size_t)tok * ND);
    float4* d = (float4*)(emb + (size_t)bt * ND);
    d[threadIdx.x] = s[threadIdx.x];   // 128 threads * 16B = 512 floats
}

// ---------------- generic split-bf16 GEMM: C[M][N] = A[M][K] @ B[N][K]^T + bias ----------------
// 3-term emulation: Ahi*Bhi + Alo*Bhi + Ahi*Blo  (error ~2^-18 relative)
// APK/BPK: operand is pre-split packed u32 (hi<<16|lo) -> staging is load+shift only.
// BM=BN=128, BK=64, 256 threads = 4 waves (2x2 of 64x64), 16x16x32 bf16 MFMA.
template<bool ARGMAX, bool APK, bool BPK>
__global__ __launch_bounds__(256, 2) void k_gemm(
    const void* __restrict__ Av,    // [M][K] row-major (fp32 or packed u32)
    const void* __restrict__ Bv,    // [N][K] row-major (fp32 or packed u32)
    const float* __restrict__ bias1,
    const float* __restrict__ bias2,
    float* __restrict__ C,          // [M][N]
    u64* __restrict__ argm,
    int M, int N, int K, int NB) {
    __shared__ u16 sAh[128 * 64], sAl[128 * 64], sBh[128 * 64], sBl[128 * 64];
    int tid = threadIdx.x, lane = tid & 63, w = tid >> 6;
    int wm = w >> 1, wn = w & 1;

    // XCD-affinity swizzle: the 8 m-blocks sharing one n-slice land on the same XCD
    int bid = blockIdx.x;
    int full = NB >> 3;
    int thresh = full << 6;
    int m_idx, n_idx;
    if (bid < thresh) {
        int g = bid >> 6, r = bid & 63;
        n_idx = g * 8 + (r & 7);
        m_idx = r >> 3;
    } else {
        int r2 = bid - thresh;
        int nrem = NB - (full << 3);
        n_idx = (full << 3) + r2 % nrem;
        m_idx = r2 / nrem;
    }
    int mbase = m_idx * 128, nbase = n_idx * 128;

    f32x4 acc[4][4];
    #pragma unroll
    for (int i = 0; i < 4; ++i)
        #pragma unroll
        for (int j = 0; j < 4; ++j) acc[i][j] = (f32x4){0.f, 0.f, 0.f, 0.f};

    const int lc = lane & 15, lk4 = lane >> 4;

    #pragma unroll 1
    for (int kc = 0; kc < K; kc += 64) {
        // -------- stage A & B chunk -> bf16 hi/lo into swizzled LDS --------
        #pragma unroll
        for (int it = 0; it < 4; ++it) {
            int gi = tid + it * 256;          // 0..1023
            int row = gi >> 3, gin = gi & 7;  // 128 rows x 8 granules(8 elems)
            int gs8 = ((gin ^ (row & 7)) << 3);
            {
                short8 h8, l8;
                if (APK) {
                    const u32* src = (const u32*)Av + (size_t)(mbase + row) * K + kc + gin * 8;
                    uint4 p0 = *(const uint4*)(src);
                    uint4 p1 = *(const uint4*)(src + 4);
                    u32 pv[8] = {p0.x, p0.y, p0.z, p0.w, p1.x, p1.y, p1.z, p1.w};
                    #pragma unroll
                    for (int e = 0; e < 8; ++e) {
                        h8[e] = (short)(u16)(pv[e] >> 16);
                        l8[e] = (short)(u16)(pv[e] & 0xFFFFu);
                    }
                } else {
                    const float* src = (const float*)Av + (size_t)(mbase + row) * K + kc + gin * 8;
                    float4 f0 = *(const float4*)(src);
                    float4 f1 = *(const float4*)(src + 4);
                    float fv[8] = {f0.x, f0.y, f0.z, f0.w, f1.x, f1.y, f1.z, f1.w};
                    #pragma unroll
                    for (int e = 0; e < 8; ++e) {
                        u16 hi = f2bf(fv[e]);
                        h8[e] = (short)hi;
                        l8[e] = (short)f2bf(fv[e] - bf2f(hi));
                    }
                }
                *(short8*)&sAh[row * 64 + gs8] = h8;
                *(short8*)&sAl[row * 64 + gs8] = l8;
            }
            {
                int n = nbase + row;
                short8 h8, l8;
                if (n < N) {
                    if (BPK) {
                        const u32* src = (const u32*)Bv + (size_t)n * K + kc + gin * 8;
                        uint4 p0 = *(const uint4*)(src);
                        uint4 p1 = *(const uint4*)(src + 4);
                        u32 pv[8] = {p0.x, p0.y, p0.z, p0.w, p1.x, p1.y, p1.z, p1.w};
                        #pragma unroll
                        for (int e = 0; e < 8; ++e) {
                            h8[e] = (short)(u16)(pv[e] >> 16);
                            l8[e] = (short)(u16)(pv[e] & 0xFFFFu);
                        }
                    } else {
                        const float* src = (const float*)Bv + (size_t)n * K + kc + gin * 8;
                        float4 f0 = *(const float4*)(src);
                        float4 f1 = *(const float4*)(src + 4);
                        float fv[8] = {f0.x, f0.y, f0.z, f0.w, f1.x, f1.y, f1.z, f1.w};
                        #pragma unroll
                        for (int e = 0; e < 8; ++e) {
                            u16 hi = f2bf(fv[e]);
                            h8[e] = (short)hi;
                            l8[e] = (short)f2bf(fv[e] - bf2f(hi));
                        }
                    }
                } else {
                    #pragma unroll
                    for (int e = 0; e < 8; ++e) { h8[e] = 0; l8[e] = 0; }
                }
                *(short8*)&sBh[row * 64 + gs8] = h8;
                *(short8*)&sBl[row * 64 + gs8] = l8;
            }
        }
        __syncthreads();
        // -------- MFMA on the chunk --------
        #pragma unroll
        for (int ks = 0; ks < 2; ++ks) {
            short8 ah[4], al[4], bh[4], bl[4];
            #pragma unroll
            for (int mi = 0; mi < 4; ++mi) {
                int r = wm * 64 + mi * 16 + lc;
                int gs8 = (((ks * 4 + lk4) ^ (r & 7)) << 3);
                ah[mi] = *(const short8*)&sAh[r * 64 + gs8];
                al[mi] = *(const short8*)&sAl[r * 64 + gs8];
            }
            #pragma unroll
            for (int ni = 0; ni < 4; ++ni) {
                int r = wn * 64 + ni * 16 + lc;
                int gs8 = (((ks * 4 + lk4) ^ (r & 7)) << 3);
                bh[ni] = *(const short8*)&sBh[r * 64 + gs8];
                bl[ni] = *(const short8*)&sBl[r * 64 + gs8];
            }
            #pragma unroll
            for (int mi = 0; mi < 4; ++mi)
                #pragma unroll
                for (int ni = 0; ni < 4; ++ni) {
                    acc[mi][ni] = __builtin_amdgcn_mfma_f32_16x16x32_bf16(ah[mi], bh[ni], acc[mi][ni], 0, 0, 0);
                    acc[mi][ni] = __builtin_amdgcn_mfma_f32_16x16x32_bf16(al[mi], bh[ni], acc[mi][ni], 0, 0, 0);
                    acc[mi][ni] = __builtin_amdgcn_mfma_f32_16x16x32_bf16(ah[mi], bl[ni], acc[mi][ni], 0, 0, 0);
                }
        }
        __syncthreads();
    }

    // -------- epilogue: bias, store, fused argmax --------
    float bsum[4];
    int cols[4];
    #pragma unroll
    for (int ni = 0; ni < 4; ++ni) {
        int col = nbase + wn * 64 + ni * 16 + lc;
        cols[ni] = col;
        float bv = 0.f;
        if (col < N) { bv = bias1[col]; if (bias2) bv += bias2[col]; }
        bsum[ni] = bv;
    }
    #pragma unroll
    for (int mi = 0; mi < 4; ++mi) {
        #pragma unroll
        for (int r_ = 0; r_ < 4; ++r_) {
            int row = mbase + wm * 64 + mi * 16 + (lk4 << 2) + r_;   // m89 C/D layout
            float* crow = C + (size_t)row * N;
            u64 best = 0ull;
            #pragma unroll
            for (int ni = 0; ni < 4; ++ni) {
                if (cols[ni] < N) {
                    float v = acc[mi][ni][r_] + bsum[ni];
                    crow[cols[ni]] = v;
                    if (ARGMAX) {
                        u32 bits = __builtin_bit_cast(u32, v);
                        u32 mono = (bits & 0x80000000u) ? ~bits : (bits | 0x80000000u);
                        u64 p = ((u64)mono << 32) | (u64)(0xFFFFFFFFu - (u32)cols[ni]);
                        best = best > p ? best : p;
                    }
                }
            }
            if (ARGMAX) {
                #pragma unroll
                for (int s = 1; s < 16; s <<= 1) {
                    u64 o = __shfl_xor((unsigned long long)best, s, 64);
                    best = best > o ? best : o;
                }
                if (lc == 0) atomicMax(&argm[row], best);
            }
        }
    }
}

// ---------------- K4: LSTM, weight-stationary, 32 blocks x 16 hidden units ----------------
// Fence-free cross-block exchange: ALL cross-block data goes through relaxed
// AGENT-scope atomics (cache-bypassing, coherence-point ops) -> no buffer_wbl2/
// buffer_inv per step, L2 stays warm. Per-(step,block) flags replace the
// counter barrier. Double-buffered H makes the pipeline race-free.
// hs is emitted PRE-SPLIT packed ((hi<<16)|lo) for the logits GEMM.
__global__ __launch_bounds__(256, 1) void k_lstm(
    const float* __restrict__ xg, const float* __restrict__ h0,
    const u16* __restrict__ Whi, const u16* __restrict__ Wlo,
    u32* __restrict__ hs_pk,
    u32* __restrict__ H,            // [2][16*512] packed (hi<<16)|lo
    u32* __restrict__ flags) {      // [NT][LSTM_NBLK]
    __shared__ u16 hhi[16 * 512];   // [batch][k], granule-XOR swizzled
    __shared__ u16 hlo[16 * 512];
    __shared__ float g_lds[4 * 256];  // [gate][batch*16+unit]

    const int tid = threadIdx.x;
    const int lane = tid & 63, w = tid >> 6;       // wave = gate type (i,f,g,o)
    const int blk = blockIdx.x;
    const int u0 = blk * UPB;
    const int lc = lane & 15, lk4 = lane >> 4;
    const int bown = tid >> 4, uown = tid & 15;    // owned (batch, unit)

    // ---- weights -> registers (once) ----
    short8 bh[16], bl[16];
    {
        size_t base = (size_t)(w * NH + u0 + lc) * NH + lk4 * 8;
        #pragma unroll
        for (int kk = 0; kk < 16; ++kk) {
            bh[kk] = *(const short8*)(Whi + base + kk * 32);
            bl[kk] = *(const short8*)(Wlo + base + kk * 32);
        }
    }

    // ---- stage h0 -> LDS (fp32 -> hi/lo, swizzled) ----
    #pragma unroll
    for (int i = 0; i < 32; ++i) {
        int idx = i * 256 + tid;           // 0..8191
        int b = idx >> 9, k = idx & 511;
        float f = h0[b * NH + k];
        u16 hi = f2bf(f), lo = f2bf(f - bf2f(hi));
        int g = k >> 3;
        int ea = b * 512 + ((g ^ (b & 7)) << 3) + (k & 7);
        hhi[ea] = hi;
        hlo[ea] = lo;
    }
    float c = 0.f;
    __syncthreads();

    #pragma unroll 1
    for (int t = 0; t < NT; ++t) {
        // ---- gates = h @ W^T via 3-term split MFMA (3 independent acc chains) ----
        f32x4 a0 = (f32x4){0.f,0.f,0.f,0.f};
        f32x4 a1 = (f32x4){0.f,0.f,0.f,0.f};
        f32x4 a2 = (f32x4){0.f,0.f,0.f,0.f};
        #pragma unroll
        for (int kk = 0; kk < 16; ++kk) {
            int g = kk * 4 + lk4;
            int ea = lc * 512 + ((g ^ (lc & 7)) << 3);
            short8 ah = *(const short8*)&hhi[ea];
            short8 al = *(const short8*)&hlo[ea];
            a0 = __builtin_amdgcn_mfma_f32_16x16x32_bf16(ah, bh[kk], a0, 0, 0, 0);
            a1 = __builtin_amdgcn_mfma_f32_16x16x32_bf16(al, bh[kk], a1, 0, 0, 0);
            a2 = __builtin_amdgcn_mfma_f32_16x16x32_bf16(ah, bl[kk], a2, 0, 0, 0);
        }
        // D[batch = lk4*4+r][unit = lc] for gate w
        #pragma unroll
        for (int r = 0; r < 4; ++r)
            g_lds[w * 256 + (lk4 * 4 + r) * 16 + lc] = a0[r] + a1[r] + a2[r];
        __syncthreads();

        // ---- per-(batch,unit) nonlinearity; thread owns one pair ----
        const float* xrow = xg + (size_t)(bown * NT + t) * NG + u0 + uown;
        float gi = g_lds[0 * 256 + tid] + xrow[0];
        float gf = g_lds[1 * 256 + tid] + xrow[NH];
        float gg = g_lds[2 * 256 + tid] + xrow[2 * NH];
        float go = g_lds[3 * 256 + tid] + xrow[3 * NH];
        c = sigm(gf) * c + sigm(gi) * tanhf(gg);
        float h = sigm(go) * tanhf(c);
        u16 hi = f2bf(h), lo = f2bf(h - bf2f(hi));
        u32 pk = ((u32)hi << 16) | (u32)lo;
        hs_pk[(size_t)(bown * NT + t) * NH + u0 + uown] = pk;

        if (t < NT - 1) {
            const int buf = (t & 1) * 8192;
            // publish own (batch,unit) word: coherence-point store, no fence
            __hip_atomic_store(&H[buf + bown * NH + u0 + uown], pk,
                               __ATOMIC_RELAXED, __HIP_MEMORY_SCOPE_AGENT);
            asm volatile("s_waitcnt vmcnt(0)" ::: "memory");   // own store at coherence point
            __syncthreads();                                    // whole block's stores done
            if (tid == 0)
                __hip_atomic_store(&flags[t * LSTM_NBLK + blk], 1u,
                                   __ATOMIC_RELAXED, __HIP_MEMORY_SCOPE_AGENT);
            // every wave polls all 32 flags (lanes 0..31, one flag each),
            // s_sleep backoff keeps coherence-point traffic low
            if (lane < LSTM_NBLK) {
                while (__hip_atomic_load(&flags[t * LSTM_NBLK + lane],
                                         __ATOMIC_RELAXED, __HIP_MEMORY_SCOPE_AGENT) == 0) {
                    __builtin_amdgcn_s_sleep(1);
                }
            }
            asm volatile("" ::: "memory");
            // ---- read back full h, restage LDS (swizzled, b128 writes) ----
            #pragma unroll
            for (int i = 0; i < 4; ++i) {
                int grp = i * 256 + tid;            // 1024 groups of 8 elems
                int b = grp >> 6, gidx = grp & 63;  // granule index
                int ubase = gidx << 3;
                short8 h8, l8;
                #pragma unroll
                for (int e = 0; e < 8; ++e) {
                    u32 v = __hip_atomic_load(&H[buf + b * NH + ubase + e],
                                              __ATOMIC_RELAXED, __HIP_MEMORY_SCOPE_AGENT);
                    h8[e] = (short)(u16)(v >> 16);
                    l8[e] = (short)(u16)(v & 0xFFFFu);
                }
                int ea = b * 512 + ((gidx ^ (b & 7)) << 3);
                *(short8*)&hhi[ea] = h8;
                *(short8*)&hlo[ea] = l8;
            }
            __syncthreads();
        }
    }
}

// ---------------- K6: decode packed argmax -> float predictions ----------------
__global__ void k_decode(const u64* __restrict__ argm, float* __restrict__ pred) {
    int i = blockIdx.x * 256 + threadIdx.x;
    if (i < NB_B * NT) {
        u32 enc = (u32)(argm[i] & 0xFFFFFFFFull);
        pred[i] = (float)(0xFFFFFFFFu - enc);
    }
}

extern "C" void kernel_launch(void* const* d_in, const int* in_sizes, int n_in,
                              void* d_out, int out_size, void* d_ws, size_t ws_size,
                              hipStream_t stream) {
    const float* sh  = (const float*)d_in[0];
    const float* oh  = (const float*)d_in[1];
    const int*   tg  = (const int*)d_in[2];
    const float* Wc  = (const float*)d_in[3];
    const float* bc  = (const float*)d_in[4];
    const float* E   = (const float*)d_in[5];
    const float* Wih = (const float*)d_in[6];
    const float* Whh = (const float*)d_in[7];
    const float* bih = (const float*)d_in[8];
    const float* bhh = (const float*)d_in[9];
    const float* Wo  = (const float*)d_in[10];
    const float* bo  = (const float*)d_in[11];

    float* out_logits = (float*)d_out;
    float* out_pred   = out_logits + (size_t)NB_B * NT * NV;
    float* out_rep    = out_pred + NB_B * NT;

    char* ws = (char*)d_ws;
    u16*   Whi   = (u16*)(ws);                                   // 2 MB
    u16*   Wlo   = (u16*)(ws + (size_t)2  * 1024 * 1024);        // 2 MB
    float* emb   = (float*)(ws + (size_t)4  * 1024 * 1024);      // 2 MB
    float* xg    = (float*)(ws + (size_t)6  * 1024 * 1024);      // 8 MB
    u32*   hs_pk = (u32*)(ws + (size_t)14 * 1024 * 1024);        // 2 MB
    float* h0    = (float*)(ws + (size_t)16 * 1024 * 1024);      // 32 KB
    u64*   argm  = (u64*)(ws + (size_t)16 * 1024 * 1024 + 32 * 1024);   // 8 KB
    u32*   H     = (u32*)(ws + (size_t)16 * 1024 * 1024 + 40 * 1024);   // 64 KB (2 bufs)
    u32*   flags = (u32*)(ws + (size_t)16 * 1024 * 1024 + 104 * 1024);  // 8 KB
    size_t wo_off = (size_t)16 * 1024 * 1024 + 112 * 1024;
    u32*   Wo_pk = (u32*)(ws + wo_off);                          // 98.2 MB (optional)
    const bool use_bpk = ws_size >= wo_off + (size_t)NV * NH * sizeof(u32);

    k_prep<<<dim3(4096), dim3(256), 0, stream>>>(Whh, Whi, Wlo, argm, flags);
    k_combine<<<dim3(NB_B), dim3(256), 0, stream>>>(sh, oh, Wc, bc, h0, out_rep);
    k_gather<<<dim3(NB_B * NT), dim3(128), 0, stream>>>(tg, E, emb);
    // xg = emb @ W_ih^T + b_ih + b_hh   (M=1024, N=2048, K=512, NB=16)
    k_gemm<false, false, false><<<dim3(8 * 16), dim3(256), 0, stream>>>(
        emb, Wih, bih, bhh, xg, (u64*)nullptr, NB_B * NT, NG, ND, 16);
    if (use_bpk)
        k_pack_wo<<<dim3(12565), dim3(256), 0, stream>>>(Wo, Wo_pk);
    k_lstm<<<dim3(LSTM_NBLK), dim3(256), 0, stream>>>(xg, h0, Whi, Wlo, hs_pk, H, flags);
    // logits = hs @ Wo^T + bo, fused argmax  (M=1024, N=50257, K=512, NB=393)
    if (use_bpk)
        k_gemm<true, true, true><<<dim3(8 * 393), dim3(256), 0, stream>>>(
            hs_pk, Wo_pk, bo, (const float*)nullptr, out_logits, argm, NB_B * NT, NV, NH, 393);
    else
        k_gemm<true, true, false><<<dim3(8 * 393), dim3(256), 0, stream>>>(
            hs_pk, Wo, bo, (const float*)nullptr, out_logits, argm, NB_B * NT, NV, NH, 393);
    k_decode<<<dim3(4), dim3(256), 0, stream>>>(argm, out_pred);
}